// Round 23
// baseline (90.339 us; speedup 1.0000x reference)
//
#include <hip/hip_runtime.h>
#include <stdint.h>

// minerva2: echo = (F̂ Ê^T)^3 @ V, intensity = rowsum((F̂ Ê^T)^3)
// R23 = R22 (full-tile dbuf, 1 barrier/tile, R12-proven swizzle bytes) with
// QK^T and PV switched to mfma_f32_32x32x16_bf16: -17% MFMA-pipe cycles
// (8.07 vs 2x4.85 cyc per 32K FLOP), half the MFMA/cvtpk/permlane count.
// Wave (wr,wd) owns 64q x 32d; qB[2][16] full-H resident; pacc/eacc32 16-reg.

typedef unsigned short u16;
typedef __bf16 bf16x8 __attribute__((ext_vector_type(8)));
typedef float f32x4 __attribute__((ext_vector_type(4)));
typedef float f32x16 __attribute__((ext_vector_type(16)));
typedef unsigned short u16x4 __attribute__((ext_vector_type(4)));

#define NQ 8192
#define ND 16384
#define NH 256
#define NC 28
#define DCHUNK 2048
#define NDT 32       // 64-row D-tiles per chunk
#define NSLOT 8      // partial slots = 8 D-chunks (one per XCD; wd merged)

__device__ __forceinline__ u16 f2bf(float f) {
  unsigned u = __builtin_bit_cast(unsigned, f);
  u += 0x7fffu + ((u >> 16) & 1u);   // RNE
  return (u16)(u >> 16);
}

__device__ __forceinline__ unsigned cvtpk(float lo, float hi) {
  unsigned r;
  asm("v_cvt_pk_bf16_f32 %0, %1, %2" : "=v"(r) : "v"(lo), "v"(hi));
  return r;  // low16 = bf16(lo), high16 = bf16(hi)  (RNE)
}

// permlane32_swap: x[l>=32] <-> y[l<32] (q = l&31 preserved in both halves)
__device__ __forceinline__ void swap32(unsigned& x, unsigned& y) {
  asm("v_permlane32_swap_b32 %0, %1" : "+v"(x), "+v"(y));
}

__device__ __forceinline__ void gload16(const void* g, void* l) {
  // async global->LDS, 16B/lane; LDS dest = wave-uniform base + lane*16
  __builtin_amdgcn_global_load_lds(
      (__attribute__((address_space(1))) void*)g,
      (__attribute__((address_space(3))) void*)l, 16, 0, 0);
}

// ---- prep: rows 0..24575 = L2-normalize (feat->qn, exf->kn); then Vt ------
__global__ __launch_bounds__(256) void prep_kernel(
    const float* __restrict__ feat, const float* __restrict__ exf,
    const float* __restrict__ V, u16* __restrict__ qn, u16* __restrict__ kn,
    u16* __restrict__ Vt) {
  if (blockIdx.x < 6144) {
    const int wid = threadIdx.x >> 6, lane = threadIdx.x & 63;
    const int row = blockIdx.x * 4 + wid;
    const float* in = (row < NQ) ? feat + (size_t)row * NH
                                 : exf + (size_t)(row - NQ) * NH;
    u16* out = (row < NQ) ? qn + (size_t)row * NH : kn + (size_t)(row - NQ) * NH;
    float4 v = ((const float4*)in)[lane];
    float ss = v.x * v.x + v.y * v.y + v.z * v.z + v.w * v.w;
#pragma unroll
    for (int m = 1; m <= 32; m <<= 1) ss += __shfl_xor(ss, m, 64);
    const float sc = 1.0f / fmaxf(sqrtf(ss), 1e-12f);  // matches F.normalize eps
    u16x4 o;
    o.x = f2bf(v.x * sc); o.y = f2bf(v.y * sc);
    o.z = f2bf(v.z * sc); o.w = f2bf(v.w * sc);
    *(u16x4*)(out + lane * 4) = o;
  } else {
    const int d = (blockIdx.x - 6144) * 256 + threadIdx.x;  // 16384
#pragma unroll
    for (int c = 0; c < NC; ++c) Vt[(size_t)c * ND + d] = f2bf(V[(size_t)d * NC + c]);
    Vt[(size_t)28 * ND + d] = 0x3F80;  // bf16 1.0 -> echo col 28 == intensity
    Vt[(size_t)29 * ND + d] = 0;
    Vt[(size_t)30 * ND + d] = 0;
    Vt[(size_t)31 * ND + d] = 0;
  }
}

// ---------------- fused main kernel ----------------------------------------
// grid 512: dch = bid&7 (one 2MB K-chunk per XCD, L2-resident), ntile = bid>>3.
// 4 waves, 2x2: wave (wr, wd) owns q-rows [ntile*128+wr*64, +64) x
// d-rows [wd*32, +32) of each 64-row D-tile.  32x32x16 MFMA throughout.
// LDS 64KB = 2 full-tile bufs [8 kp][64 d][64B]; stored chunk p at row R =
// logical p ^ ((R>>1)&3) (same bytes as R22; only the read formula changes).
__global__ __launch_bounds__(256, 2) void fused_kernel(
    const u16* __restrict__ Qn, const u16* __restrict__ Kn,
    const u16* __restrict__ Vt, float* __restrict__ ep) {
  __shared__ alignas(16) char smem[65536];
  const int tid = threadIdx.x;
  const int wid = tid >> 6;
  const int lane = tid & 63;
  const int lane31 = lane & 31;
  const int lhalf = lane >> 5;
  const int wr = wid >> 1;
  const int wd = wid & 1;
  const int dch = blockIdx.x & 7;
  const int ntile = blockIdx.x >> 3;
  const int rowbase = ntile * 128 + wr * 64;

  // ---- Q fragments (MFMA B-operand): col q = lane31, k = lhalf*8+i ----
  bf16x8 qB[2][16];
#pragma unroll
  for (int qh = 0; qh < 2; ++qh)
#pragma unroll
    for (int ks = 0; ks < 16; ++ks)
      qB[qh][ks] = *(const bf16x8*)(Qn + (size_t)(rowbase + qh * 32 + lane31) * NH +
                                    ks * 16 + lhalf * 8);

  f32x16 eacc32[2];
  f32x16 pacc[2];
#pragma unroll
  for (int qh = 0; qh < 2; ++qh)
#pragma unroll
    for (int r = 0; r < 16; ++r) eacc32[qh][r] = 0.f;

  const u16* kc = Kn + (size_t)dch * DCHUNK * NH;
  // staging decomposition (per sub-slab r = kp): d = (tid>>6)*16 + ((tid>>2)&15),
  // stored chunk = tid&3, logical chunk = (tid&3) ^ ((tid>>3)&3)
  const int srow = (tid >> 6) * 16 + ((tid >> 2) & 15);
  const u16* kb = kc + (size_t)srow * NH + ((tid & 3) ^ ((tid >> 3) & 3)) * 8;

  // stage one FULL [64d][256k] tile -> buf as 8 sub-slabs [64d][64B]
  auto stage = [&](int buf, const u16* src0) {
#pragma unroll
    for (int r = 0; r < 8; ++r)
      gload16(src0 + r * 32,
              smem + buf * 32768 + r * 4096 + wid * 1024);
  };

  const int rsw32 = (lane31 >> 1) & 3;  // (d>>1)&3 for d = wd*32 + lane31

  // compute one staged full tile (buf): 16 k-steps of 16 (kp,h), A = K-frag
  // A layout: row d = wd*32 + lane31, k = lhalf*8+i -> logical chunk h*2+lhalf
  auto compute = [&](int buf) {
    const char* kbuf = smem + buf * 32768;
#pragma unroll
    for (int kp = 0; kp < 8; ++kp) {
#pragma unroll
      for (int h = 0; h < 2; ++h) {
        const bf16x8 A = *(const bf16x8*)(
            kbuf + kp * 4096 + (wd * 32 + lane31) * 64 +
            (((h * 2 + lhalf) ^ rsw32) << 4));
        __builtin_amdgcn_s_setprio(1);
        pacc[0] = __builtin_amdgcn_mfma_f32_32x32x16_bf16(
            A, qB[0][kp * 2 + h], pacc[0], 0, 0, 0);
        pacc[1] = __builtin_amdgcn_mfma_f32_32x32x16_bf16(
            A, qB[1][kp * 2 + h], pacc[1], 0, 0, 0);
        __builtin_amdgcn_s_setprio(0);
      }
    }
  };

  // prologue: tile 0 -> buf 0
  stage(0, kb);
  __syncthreads();

  for (int t = 0; t < NDT; ++t) {
    const int cur = t & 1;
    const int dbase = dch * DCHUNK + t * 64 + wd * 32;

#pragma unroll
    for (int qh = 0; qh < 2; ++qh)
#pragma unroll
      for (int r = 0; r < 16; ++r) pacc[qh][r] = 0.f;

    // prefetch next tile into the other buffer (drains by next barrier)
    if (t < NDT - 1) stage(cur ^ 1, kb + (size_t)(t + 1) * 64 * NH);

    // vB[w] (PV B-operand): col c = lane31, k(d) = lhalf*8+i, window w*16
    bf16x8 vB[2];
#pragma unroll
    for (int w = 0; w < 2; ++w)
      vB[w] = *(const bf16x8*)(Vt + (size_t)lane31 * ND + dbase + w * 16 +
                               lhalf * 8);

    compute(cur);

    // ---- cube (fp32) -> bf16 pack -> permlane32 transpose -> PV MFMA ----
    // pacc[qh]: q = lane31, d = (reg&3) + 8*(reg>>2) + 4*lhalf.
    // PV A-frag for window w: lane needs d = 16w + 8*lhalf + i (i=0..7):
    //   one swap32(u[2w][j], u[2w+1][j]) fills words j and j+2 for BOTH halves.
#pragma unroll
    for (int qh = 0; qh < 2; ++qh) {
      float c[16];
#pragma unroll
      for (int r = 0; r < 16; ++r) {
        const float s = pacc[qh][r];
        c[r] = s * s * s;
      }
#pragma unroll
      for (int w = 0; w < 2; ++w) {
        unsigned x0 = cvtpk(c[8 * w + 0], c[8 * w + 1]);  // u[2w][0]
        unsigned x1 = cvtpk(c[8 * w + 2], c[8 * w + 3]);  // u[2w][1]
        unsigned y0 = cvtpk(c[8 * w + 4], c[8 * w + 5]);  // u[2w+1][0]
        unsigned y1 = cvtpk(c[8 * w + 6], c[8 * w + 7]);  // u[2w+1][1]
        swap32(x0, y0);  // x0 -> words d=16w+8s+{0,1}; y0 -> +{4,5}
        swap32(x1, y1);  // x1 -> +{2,3}; y1 -> +{6,7}
        const int4 ai = {(int)x0, (int)x1, (int)y0, (int)y1};
        const bf16x8 aA = __builtin_bit_cast(bf16x8, ai);
        eacc32[qh] = __builtin_amdgcn_mfma_f32_32x32x16_bf16(
            aA, vB[w], eacc32[qh], 0, 0, 0);
      }
    }

    __syncthreads();  // orders buf reads before re-stage (t+2) and prefetch
                      // writes (drained here) before compute at t+1
  }

  // ---- epilogue: merge wd=1 into wd=0 via LDS (bufs dead), slot = dch ----
  // eacc32[qh]: q = qh*32 + (r&3)+8*(r>>2)+4*lhalf (local), col c = lane31.
  float* eml = (float*)smem;  // [2 wr][64 lanes][32 f32] = 16KB
  if (wd == 1) {
    float* dst = eml + (wr * 64 + lane) * 32;
#pragma unroll
    for (int qh = 0; qh < 2; ++qh)
#pragma unroll
      for (int r = 0; r < 4; ++r)
        *(f32x4*)(dst + qh * 16 + r * 4) =
            f32x4{eacc32[qh][r * 4], eacc32[qh][r * 4 + 1],
                  eacc32[qh][r * 4 + 2], eacc32[qh][r * 4 + 3]};
  }
  __syncthreads();
  if (wd == 0) {
    const float* src = eml + (wr * 64 + lane) * 32;
#pragma unroll
    for (int qh = 0; qh < 2; ++qh)
#pragma unroll
      for (int r = 0; r < 16; ++r) {
        const float m = eacc32[qh][r] + src[qh * 16 + r];
        const int row = rowbase + qh * 32 + (r & 3) + 8 * (r >> 2) + 4 * lhalf;
        ep[((size_t)dch * NQ + row) * 32 + lane31] = m;
      }
  }
}

// ---------------- reduce 8 partial slots -> d_out --------------------------
__global__ __launch_bounds__(256) void reduce_kernel(const float* __restrict__ ep,
                                                     float* __restrict__ out) {
  const int g = blockIdx.x * 256 + threadIdx.x;  // 8192*32
  const int q = g >> 5, c = g & 31;
  if (c < NC) {
    float s = 0.f;
#pragma unroll
    for (int k = 0; k < NSLOT; ++k) s += ep[((size_t)k * NQ + q) * 32 + c];
    out[(size_t)q * NC + c] = s;
  } else if (c == NC) {  // ones-column == intensity
    float s = 0.f;
#pragma unroll
    for (int k = 0; k < NSLOT; ++k) s += ep[((size_t)k * NQ + q) * 32 + NC];
    out[(size_t)NQ * NC + q] = s;
  }
}

extern "C" void kernel_launch(void* const* d_in, const int* in_sizes, int n_in,
                              void* d_out, int out_size, void* d_ws, size_t ws_size,
                              hipStream_t stream) {
  const float* feat = (const float*)d_in[0];  // [8192][256]
  const float* exf  = (const float*)d_in[1];  // [16384][256]
  const float* exc  = (const float*)d_in[2];  // [16384][28]
  float* out = (float*)d_out;
  char* ws = (char*)d_ws;
  // ws layout: qn 4MB | kn 8MB | vt 1MB | ep 8MB  (~21MB)
  u16* qn = (u16*)ws;
  u16* kn = (u16*)(ws + 4194304);
  u16* vt = (u16*)(ws + 12582912);
  float* ep = (float*)(ws + 13631488);

  prep_kernel<<<dim3(6208), dim3(256), 0, stream>>>(feat, exf, exc, qn, kn, vt);
  fused_kernel<<<dim3(512), dim3(256), 0, stream>>>(qn, kn, vt, ep);
  reduce_kernel<<<dim3(NQ * 32 / 256), dim3(256), 0, stream>>>(ep, out);
}

// Round 24
// 84.525 us; speedup vs baseline: 1.0688x; 1.0688x over previous
//
#include <hip/hip_runtime.h>
#include <stdint.h>

// minerva2: echo = (F̂ Ê^T)^3 @ V, intensity = rowsum((F̂ Ê^T)^3)
// R24 = R22 exactly (best: full-tile dbuf, 1 barrier/tile, 2x2 wave grid
// 64qx32d, qA[4][8] resident, R12-proven sub-slab swizzle, cvt_pk/permlane
// PV, NSLOT=8) MINUS s_setprio (isolated A/B: T5 is null-to-negative on
// barrier-lockstep GEMM structures per m190; it was never isolated here).

typedef unsigned short u16;
typedef __bf16 bf16x8 __attribute__((ext_vector_type(8)));
typedef float f32x4 __attribute__((ext_vector_type(4)));
typedef unsigned short u16x4 __attribute__((ext_vector_type(4)));

#define NQ 8192
#define ND 16384
#define NH 256
#define NC 28
#define DCHUNK 2048
#define NDT 32       // 64-row D-tiles per chunk
#define NSLOT 8      // partial slots = 8 D-chunks (one per XCD; wd merged)

__device__ __forceinline__ u16 f2bf(float f) {
  unsigned u = __builtin_bit_cast(unsigned, f);
  u += 0x7fffu + ((u >> 16) & 1u);   // RNE
  return (u16)(u >> 16);
}

__device__ __forceinline__ unsigned cvtpk(float lo, float hi) {
  unsigned r;
  asm("v_cvt_pk_bf16_f32 %0, %1, %2" : "=v"(r) : "v"(lo), "v"(hi));
  return r;  // low16 = bf16(lo), high16 = bf16(hi)  (RNE)
}

// After: x = [x.r0, x.r2, y.r0, y.r2] (by 16-lane row), y = [x.r1, x.r3, y.r1, y.r3]
__device__ __forceinline__ void swap2(unsigned& x, unsigned& y) {
  asm("v_permlane32_swap_b32 %0, %1" : "+v"(x), "+v"(y));  // x.r23 <-> y.r01
  asm("v_permlane16_swap_b32 %0, %1" : "+v"(x), "+v"(y));  // x.r1<->y.r0, x.r3<->y.r2
}

__device__ __forceinline__ void gload16(const void* g, void* l) {
  // async global->LDS, 16B/lane; LDS dest = wave-uniform base + lane*16
  __builtin_amdgcn_global_load_lds(
      (__attribute__((address_space(1))) void*)g,
      (__attribute__((address_space(3))) void*)l, 16, 0, 0);
}

// ---- prep: rows 0..24575 = L2-normalize (feat->qn, exf->kn); then Vt ------
__global__ __launch_bounds__(256) void prep_kernel(
    const float* __restrict__ feat, const float* __restrict__ exf,
    const float* __restrict__ V, u16* __restrict__ qn, u16* __restrict__ kn,
    u16* __restrict__ Vt) {
  if (blockIdx.x < 6144) {
    const int wid = threadIdx.x >> 6, lane = threadIdx.x & 63;
    const int row = blockIdx.x * 4 + wid;
    const float* in = (row < NQ) ? feat + (size_t)row * NH
                                 : exf + (size_t)(row - NQ) * NH;
    u16* out = (row < NQ) ? qn + (size_t)row * NH : kn + (size_t)(row - NQ) * NH;
    float4 v = ((const float4*)in)[lane];
    float ss = v.x * v.x + v.y * v.y + v.z * v.z + v.w * v.w;
#pragma unroll
    for (int m = 1; m <= 32; m <<= 1) ss += __shfl_xor(ss, m, 64);
    const float sc = 1.0f / fmaxf(sqrtf(ss), 1e-12f);  // matches F.normalize eps
    u16x4 o;
    o.x = f2bf(v.x * sc); o.y = f2bf(v.y * sc);
    o.z = f2bf(v.z * sc); o.w = f2bf(v.w * sc);
    *(u16x4*)(out + lane * 4) = o;
  } else {
    const int d = (blockIdx.x - 6144) * 256 + threadIdx.x;  // 16384
#pragma unroll
    for (int c = 0; c < NC; ++c) Vt[(size_t)c * ND + d] = f2bf(V[(size_t)d * NC + c]);
    Vt[(size_t)28 * ND + d] = 0x3F80;  // bf16 1.0 -> echo col 28 == intensity
    Vt[(size_t)29 * ND + d] = 0;
    Vt[(size_t)30 * ND + d] = 0;
    Vt[(size_t)31 * ND + d] = 0;
  }
}

// ---------------- fused main kernel ----------------------------------------
// grid 512: dch = bid&7 (one 2MB K-chunk per XCD, L2-resident), ntile = bid>>3.
// 4 waves, 2x2: wave (wr, wd) owns q-rows [ntile*128+wr*64, +64) x
// d-rows [wd*32, +32) of each 64-row D-tile.
// Q (all H) in registers. LDS 64KB = 2 full-tile bufs [8 k2][64 d][64B].
// Sub-slab swizzle (R12-proven): stored chunk p at row R = logical p^((R>>1)&3).
__global__ __launch_bounds__(256, 2) void fused_kernel(
    const u16* __restrict__ Qn, const u16* __restrict__ Kn,
    const u16* __restrict__ Vt, float* __restrict__ ep) {
  __shared__ alignas(16) char smem[65536];
  const int tid = threadIdx.x;
  const int wid = tid >> 6;
  const int lane = tid & 63;
  const int l16 = lane & 15;
  const int lg = lane >> 4;
  const int wr = wid >> 1;
  const int wd = wid & 1;
  const int dch = blockIdx.x & 7;
  const int ntile = blockIdx.x >> 3;
  const int rowbase = ntile * 128 + wr * 64;

  // ---- Q fragments, 64 rows x all H, in registers (MFMA B-operand) ----
  bf16x8 qA[4][8];
#pragma unroll
  for (int mb = 0; mb < 4; ++mb)
#pragma unroll
    for (int ks = 0; ks < 8; ++ks)
      qA[mb][ks] = *(const bf16x8*)(Qn + (size_t)(rowbase + mb * 16 + l16) * NH +
                                    ks * 32 + lg * 8);

  f32x4 eacc[4][2];
#pragma unroll
  for (int mb = 0; mb < 4; ++mb) {
    eacc[mb][0] = f32x4{0.f, 0.f, 0.f, 0.f};
    eacc[mb][1] = f32x4{0.f, 0.f, 0.f, 0.f};
  }
  f32x4 sacc[4][2];

  const u16* kc = Kn + (size_t)dch * DCHUNK * NH;
  // staging decomposition (per sub-slab r = k2): d = (tid>>6)*16 + ((tid>>2)&15),
  // stored chunk = tid&3, logical chunk = (tid&3) ^ ((tid>>3)&3)
  const int srow = (tid >> 6) * 16 + ((tid >> 2) & 15);
  const u16* kb = kc + (size_t)srow * NH + ((tid & 3) ^ ((tid >> 3) & 3)) * 8;

  // stage one FULL [64d][256k] tile -> buf as 8 sub-slabs [64d][64B]
  auto stage = [&](int buf, const u16* src0) {
#pragma unroll
    for (int r = 0; r < 8; ++r)
      gload16(src0 + r * 32,
              smem + buf * 32768 + r * 4096 + wid * 1024);
  };

  const int rsw = (l16 >> 1) & 3;  // (row>>1)&3 for row = wd*32 + nb*16 + l16

  // compute one staged full tile (buf): 8 k2-steps of 32k each
  auto compute = [&](int buf) {
    const char* kbuf = smem + buf * 32768;
#pragma unroll
    for (int k2 = 0; k2 < 8; ++k2) {
      bf16x8 B[2];
#pragma unroll
      for (int nb = 0; nb < 2; ++nb)
        B[nb] = *(const bf16x8*)(kbuf + k2 * 4096 + (wd * 32 + nb * 16 + l16) * 64 +
                                 ((lg ^ rsw) << 4));
#pragma unroll
      for (int mb = 0; mb < 4; ++mb)
#pragma unroll
        for (int nb = 0; nb < 2; ++nb)
          sacc[mb][nb] = __builtin_amdgcn_mfma_f32_16x16x32_bf16(
              B[nb], qA[mb][k2], sacc[mb][nb], 0, 0, 0);
    }
  };

  // prologue: tile 0 -> buf 0
  stage(0, kb);
  __syncthreads();

  for (int t = 0; t < NDT; ++t) {
    const int cur = t & 1;
    const int dbase = dch * DCHUNK + t * 64 + wd * 32;

#pragma unroll
    for (int mb = 0; mb < 4; ++mb) {
      sacc[mb][0] = f32x4{0.f, 0.f, 0.f, 0.f};
      sacc[mb][1] = f32x4{0.f, 0.f, 0.f, 0.f};
    }

    // prefetch next tile into the other buffer (drains by next barrier,
    // hidden under this tile's full compute + PV)
    if (t < NDT - 1) stage(cur ^ 1, kb + (size_t)(t + 1) * 64 * NH);

    // vB loads: consumed in PV; latency hidden under compute
    bf16x8 vB[2];
#pragma unroll
    for (int cn = 0; cn < 2; ++cn)
      vB[cn] = *(const bf16x8*)(Vt + (size_t)(cn * 16 + l16) * ND + dbase + lg * 8);

    compute(cur);

    // ---- cube (fp32) -> bf16 pack -> permlane transpose -> PV MFMA ----
    // sacc[mb][nb]: q = l16, d = wd*32 + nb*16 + lg*4 + r.  (LDS-free)
#pragma unroll
    for (int mb = 0; mb < 4; ++mb) {
      f32x4 sx = sacc[mb][0];
      f32x4 sy = sacc[mb][1];
      f32x4 cx = sx * sx * sx;
      f32x4 cy = sy * sy * sy;
      unsigned x0 = cvtpk(cx[0], cx[1]);  // d = 4lg+0,1   (nb = 0)
      unsigned x1 = cvtpk(cx[2], cx[3]);  // d = 4lg+2,3
      unsigned y0 = cvtpk(cy[0], cy[1]);  // same, nb = 1
      unsigned y1 = cvtpk(cy[2], cy[3]);
      swap2(x0, y0);  // x0 -> a0 (k 8g+0,1), y0 -> a2 (k 8g+4,5)
      swap2(x1, y1);  // x1 -> a1 (k 8g+2,3), y1 -> a3 (k 8g+6,7)
      const int4 ai = {(int)x0, (int)x1, (int)y0, (int)y1};
      const bf16x8 aA = __builtin_bit_cast(bf16x8, ai);
#pragma unroll
      for (int cn = 0; cn < 2; ++cn)
        eacc[mb][cn] = __builtin_amdgcn_mfma_f32_16x16x32_bf16(
            aA, vB[cn], eacc[mb][cn], 0, 0, 0);
    }

    // single barrier per tile: orders (a) this tile's buf reads before its
    // re-stage at t+2 (issued after this barrier), (b) the prefetch writes
    // (vmcnt-drained here) before compute(cur^1) at t+1.
    __syncthreads();
  }

  // ---- epilogue: merge wd=1 into wd=0 via LDS (bufs dead), slot = dch ----
  float* eml = (float*)smem;  // [2 wr][64 lanes][36 dwords] = 18KB (36: bank pad)
  if (wd == 1) {
    float* dst = eml + (wr * 64 + lane) * 36;
#pragma unroll
    for (int mb = 0; mb < 4; ++mb)
#pragma unroll
      for (int cn = 0; cn < 2; ++cn)
        *(f32x4*)(dst + (mb * 2 + cn) * 4) = eacc[mb][cn];
  }
  __syncthreads();
  if (wd == 0) {
    const float* src = eml + (wr * 64 + lane) * 36;
#pragma unroll
    for (int mb = 0; mb < 4; ++mb)
#pragma unroll
      for (int cn = 0; cn < 2; ++cn) {
        const f32x4 m = eacc[mb][cn] + *(const f32x4*)(src + (mb * 2 + cn) * 4);
#pragma unroll
        for (int r = 0; r < 4; ++r) {
          const int row = rowbase + mb * 16 + lg * 4 + r;
          ep[((size_t)dch * NQ + row) * 32 + cn * 16 + l16] = m[r];
        }
      }
  }
}

// ---------------- reduce 8 partial slots -> d_out --------------------------
__global__ __launch_bounds__(256) void reduce_kernel(const float* __restrict__ ep,
                                                     float* __restrict__ out) {
  const int g = blockIdx.x * 256 + threadIdx.x;  // 8192*32
  const int q = g >> 5, c = g & 31;
  if (c < NC) {
    float s = 0.f;
#pragma unroll
    for (int k = 0; k < NSLOT; ++k) s += ep[((size_t)k * NQ + q) * 32 + c];
    out[(size_t)q * NC + c] = s;
  } else if (c == NC) {  // ones-column == intensity
    float s = 0.f;
#pragma unroll
    for (int k = 0; k < NSLOT; ++k) s += ep[((size_t)k * NQ + q) * 32 + NC];
    out[(size_t)NQ * NC + q] = s;
  }
}

extern "C" void kernel_launch(void* const* d_in, const int* in_sizes, int n_in,
                              void* d_out, int out_size, void* d_ws, size_t ws_size,
                              hipStream_t stream) {
  const float* feat = (const float*)d_in[0];  // [8192][256]
  const float* exf  = (const float*)d_in[1];  // [16384][256]
  const float* exc  = (const float*)d_in[2];  // [16384][28]
  float* out = (float*)d_out;
  char* ws = (char*)d_ws;
  // ws layout: qn 4MB | kn 8MB | vt 1MB | ep 8MB  (~21MB)
  u16* qn = (u16*)ws;
  u16* kn = (u16*)(ws + 4194304);
  u16* vt = (u16*)(ws + 12582912);
  float* ep = (float*)(ws + 13631488);

  prep_kernel<<<dim3(6208), dim3(256), 0, stream>>>(feat, exf, exc, qn, kn, vt);
  fused_kernel<<<dim3(512), dim3(256), 0, stream>>>(qn, kn, vt, ep);
  reduce_kernel<<<dim3(NQ * 32 / 256), dim3(256), 0, stream>>>(ep, out);
}

// Round 25
// 82.021 us; speedup vs baseline: 1.1014x; 1.0305x over previous
//
#include <hip/hip_runtime.h>
#include <stdint.h>

// minerva2: echo = (F̂ Ê^T)^3 @ V, intensity = rowsum((F̂ Ê^T)^3)
// FINAL = R22 (session best, 82.0us total / 72.2us fused):
//   - prep fusion: L2-normalize feat/exf -> bf16, V -> Vt^T with ones-column
//     (intensity computed free as echo col 28)
//   - fused flash-style kernel: grid 512 (dch = bid&7 -> XCD-local 2MB K chunk,
//     L2-resident), 4 waves 2x2 (64q x 32d), Q full-H resident in registers,
//     full-tile double-buffered LDS (2x32KB), 1 barrier/tile,
//     R12-proven zero-conflict sub-slab swizzle, swapped QK^T (S^T) +
//     in-register cube/cvt_pk/permlane transpose -> PV MFMA, setprio on QK
//     (A/B-verified +1.5us), NSLOT=8 partials
//   - reduce: 8-slot sum -> d_out
// Verified: absmax 3.9e-3 (threshold 1.05e-2), SQ_LDS_BANK_CONFLICT = 0,
// no spill (VGPR 116, FETCH 21MB / WRITE 8.2MB), MfmaUtil 46%.

typedef unsigned short u16;
typedef __bf16 bf16x8 __attribute__((ext_vector_type(8)));
typedef float f32x4 __attribute__((ext_vector_type(4)));
typedef unsigned short u16x4 __attribute__((ext_vector_type(4)));

#define NQ 8192
#define ND 16384
#define NH 256
#define NC 28
#define DCHUNK 2048
#define NDT 32       // 64-row D-tiles per chunk
#define NSLOT 8      // partial slots = 8 D-chunks (one per XCD; wd merged)

__device__ __forceinline__ u16 f2bf(float f) {
  unsigned u = __builtin_bit_cast(unsigned, f);
  u += 0x7fffu + ((u >> 16) & 1u);   // RNE
  return (u16)(u >> 16);
}

__device__ __forceinline__ unsigned cvtpk(float lo, float hi) {
  unsigned r;
  asm("v_cvt_pk_bf16_f32 %0, %1, %2" : "=v"(r) : "v"(lo), "v"(hi));
  return r;  // low16 = bf16(lo), high16 = bf16(hi)  (RNE)
}

// After: x = [x.r0, x.r2, y.r0, y.r2] (by 16-lane row), y = [x.r1, x.r3, y.r1, y.r3]
__device__ __forceinline__ void swap2(unsigned& x, unsigned& y) {
  asm("v_permlane32_swap_b32 %0, %1" : "+v"(x), "+v"(y));  // x.r23 <-> y.r01
  asm("v_permlane16_swap_b32 %0, %1" : "+v"(x), "+v"(y));  // x.r1<->y.r0, x.r3<->y.r2
}

__device__ __forceinline__ void gload16(const void* g, void* l) {
  // async global->LDS, 16B/lane; LDS dest = wave-uniform base + lane*16
  __builtin_amdgcn_global_load_lds(
      (__attribute__((address_space(1))) void*)g,
      (__attribute__((address_space(3))) void*)l, 16, 0, 0);
}

// ---- prep: rows 0..24575 = L2-normalize (feat->qn, exf->kn); then Vt ------
__global__ __launch_bounds__(256) void prep_kernel(
    const float* __restrict__ feat, const float* __restrict__ exf,
    const float* __restrict__ V, u16* __restrict__ qn, u16* __restrict__ kn,
    u16* __restrict__ Vt) {
  if (blockIdx.x < 6144) {
    const int wid = threadIdx.x >> 6, lane = threadIdx.x & 63;
    const int row = blockIdx.x * 4 + wid;
    const float* in = (row < NQ) ? feat + (size_t)row * NH
                                 : exf + (size_t)(row - NQ) * NH;
    u16* out = (row < NQ) ? qn + (size_t)row * NH : kn + (size_t)(row - NQ) * NH;
    float4 v = ((const float4*)in)[lane];
    float ss = v.x * v.x + v.y * v.y + v.z * v.z + v.w * v.w;
#pragma unroll
    for (int m = 1; m <= 32; m <<= 1) ss += __shfl_xor(ss, m, 64);
    const float sc = 1.0f / fmaxf(sqrtf(ss), 1e-12f);  // matches F.normalize eps
    u16x4 o;
    o.x = f2bf(v.x * sc); o.y = f2bf(v.y * sc);
    o.z = f2bf(v.z * sc); o.w = f2bf(v.w * sc);
    *(u16x4*)(out + lane * 4) = o;
  } else {
    const int d = (blockIdx.x - 6144) * 256 + threadIdx.x;  // 16384
#pragma unroll
    for (int c = 0; c < NC; ++c) Vt[(size_t)c * ND + d] = f2bf(V[(size_t)d * NC + c]);
    Vt[(size_t)28 * ND + d] = 0x3F80;  // bf16 1.0 -> echo col 28 == intensity
    Vt[(size_t)29 * ND + d] = 0;
    Vt[(size_t)30 * ND + d] = 0;
    Vt[(size_t)31 * ND + d] = 0;
  }
}

// ---------------- fused main kernel ----------------------------------------
// grid 512: dch = bid&7 (one 2MB K-chunk per XCD, L2-resident), ntile = bid>>3.
// 4 waves, 2x2: wave (wr, wd) owns q-rows [ntile*128+wr*64, +64) x
// d-rows [wd*32, +32) of each 64-row D-tile.
// Q (all H) in registers. LDS 64KB = 2 full-tile bufs [8 k2][64 d][64B].
// Sub-slab swizzle (R12-proven): stored chunk p at row R = logical p^((R>>1)&3).
__global__ __launch_bounds__(256, 2) void fused_kernel(
    const u16* __restrict__ Qn, const u16* __restrict__ Kn,
    const u16* __restrict__ Vt, float* __restrict__ ep) {
  __shared__ alignas(16) char smem[65536];
  const int tid = threadIdx.x;
  const int wid = tid >> 6;
  const int lane = tid & 63;
  const int l16 = lane & 15;
  const int lg = lane >> 4;
  const int wr = wid >> 1;
  const int wd = wid & 1;
  const int dch = blockIdx.x & 7;
  const int ntile = blockIdx.x >> 3;
  const int rowbase = ntile * 128 + wr * 64;

  // ---- Q fragments, 64 rows x all H, in registers (MFMA B-operand) ----
  bf16x8 qA[4][8];
#pragma unroll
  for (int mb = 0; mb < 4; ++mb)
#pragma unroll
    for (int ks = 0; ks < 8; ++ks)
      qA[mb][ks] = *(const bf16x8*)(Qn + (size_t)(rowbase + mb * 16 + l16) * NH +
                                    ks * 32 + lg * 8);

  f32x4 eacc[4][2];
#pragma unroll
  for (int mb = 0; mb < 4; ++mb) {
    eacc[mb][0] = f32x4{0.f, 0.f, 0.f, 0.f};
    eacc[mb][1] = f32x4{0.f, 0.f, 0.f, 0.f};
  }
  f32x4 sacc[4][2];

  const u16* kc = Kn + (size_t)dch * DCHUNK * NH;
  // staging decomposition (per sub-slab r = k2): d = (tid>>6)*16 + ((tid>>2)&15),
  // stored chunk = tid&3, logical chunk = (tid&3) ^ ((tid>>3)&3)
  const int srow = (tid >> 6) * 16 + ((tid >> 2) & 15);
  const u16* kb = kc + (size_t)srow * NH + ((tid & 3) ^ ((tid >> 3) & 3)) * 8;

  // stage one FULL [64d][256k] tile -> buf as 8 sub-slabs [64d][64B]
  auto stage = [&](int buf, const u16* src0) {
#pragma unroll
    for (int r = 0; r < 8; ++r)
      gload16(src0 + r * 32,
              smem + buf * 32768 + r * 4096 + wid * 1024);
  };

  const int rsw = (l16 >> 1) & 3;  // (row>>1)&3 for row = wd*32 + nb*16 + l16

  // compute one staged full tile (buf): 8 k2-steps of 32k each
  auto compute = [&](int buf) {
    const char* kbuf = smem + buf * 32768;
#pragma unroll
    for (int k2 = 0; k2 < 8; ++k2) {
      bf16x8 B[2];
#pragma unroll
      for (int nb = 0; nb < 2; ++nb)
        B[nb] = *(const bf16x8*)(kbuf + k2 * 4096 + (wd * 32 + nb * 16 + l16) * 64 +
                                 ((lg ^ rsw) << 4));
      __builtin_amdgcn_s_setprio(1);
#pragma unroll
      for (int mb = 0; mb < 4; ++mb)
#pragma unroll
        for (int nb = 0; nb < 2; ++nb)
          sacc[mb][nb] = __builtin_amdgcn_mfma_f32_16x16x32_bf16(
              B[nb], qA[mb][k2], sacc[mb][nb], 0, 0, 0);
      __builtin_amdgcn_s_setprio(0);
    }
  };

  // prologue: tile 0 -> buf 0
  stage(0, kb);
  __syncthreads();

  for (int t = 0; t < NDT; ++t) {
    const int cur = t & 1;
    const int dbase = dch * DCHUNK + t * 64 + wd * 32;

#pragma unroll
    for (int mb = 0; mb < 4; ++mb) {
      sacc[mb][0] = f32x4{0.f, 0.f, 0.f, 0.f};
      sacc[mb][1] = f32x4{0.f, 0.f, 0.f, 0.f};
    }

    // prefetch next tile into the other buffer (drains by next barrier,
    // hidden under this tile's full compute + PV)
    if (t < NDT - 1) stage(cur ^ 1, kb + (size_t)(t + 1) * 64 * NH);

    // vB loads: consumed in PV; latency hidden under compute
    bf16x8 vB[2];
#pragma unroll
    for (int cn = 0; cn < 2; ++cn)
      vB[cn] = *(const bf16x8*)(Vt + (size_t)(cn * 16 + l16) * ND + dbase + lg * 8);

    compute(cur);

    // ---- cube (fp32) -> bf16 pack -> permlane transpose -> PV MFMA ----
    // sacc[mb][nb]: q = l16, d = wd*32 + nb*16 + lg*4 + r.  (LDS-free)
#pragma unroll
    for (int mb = 0; mb < 4; ++mb) {
      f32x4 sx = sacc[mb][0];
      f32x4 sy = sacc[mb][1];
      f32x4 cx = sx * sx * sx;
      f32x4 cy = sy * sy * sy;
      unsigned x0 = cvtpk(cx[0], cx[1]);  // d = 4lg+0,1   (nb = 0)
      unsigned x1 = cvtpk(cx[2], cx[3]);  // d = 4lg+2,3
      unsigned y0 = cvtpk(cy[0], cy[1]);  // same, nb = 1
      unsigned y1 = cvtpk(cy[2], cy[3]);
      swap2(x0, y0);  // x0 -> a0 (k 8g+0,1), y0 -> a2 (k 8g+4,5)
      swap2(x1, y1);  // x1 -> a1 (k 8g+2,3), y1 -> a3 (k 8g+6,7)
      const int4 ai = {(int)x0, (int)x1, (int)y0, (int)y1};
      const bf16x8 aA = __builtin_bit_cast(bf16x8, ai);
#pragma unroll
      for (int cn = 0; cn < 2; ++cn)
        eacc[mb][cn] = __builtin_amdgcn_mfma_f32_16x16x32_bf16(
            aA, vB[cn], eacc[mb][cn], 0, 0, 0);
    }

    // single barrier per tile: orders (a) this tile's buf reads before its
    // re-stage at t+2 (issued after this barrier), (b) the prefetch writes
    // (vmcnt-drained here) before compute(cur^1) at t+1.
    __syncthreads();
  }

  // ---- epilogue: merge wd=1 into wd=0 via LDS (bufs dead), slot = dch ----
  float* eml = (float*)smem;  // [2 wr][64 lanes][36 dwords] = 18KB
  if (wd == 1) {
    float* dst = eml + (wr * 64 + lane) * 36;
#pragma unroll
    for (int mb = 0; mb < 4; ++mb)
#pragma unroll
      for (int cn = 0; cn < 2; ++cn)
        *(f32x4*)(dst + (mb * 2 + cn) * 4) = eacc[mb][cn];
  }
  __syncthreads();
  if (wd == 0) {
    const float* src = eml + (wr * 64 + lane) * 36;
#pragma unroll
    for (int mb = 0; mb < 4; ++mb)
#pragma unroll
      for (int cn = 0; cn < 2; ++cn) {
        const f32x4 m = eacc[mb][cn] + *(const f32x4*)(src + (mb * 2 + cn) * 4);
#pragma unroll
        for (int r = 0; r < 4; ++r) {
          const int row = rowbase + mb * 16 + lg * 4 + r;
          ep[((size_t)dch * NQ + row) * 32 + cn * 16 + l16] = m[r];
        }
      }
  }
}

// ---------------- reduce 8 partial slots -> d_out --------------------------
__global__ __launch_bounds__(256) void reduce_kernel(const float* __restrict__ ep,
                                                     float* __restrict__ out) {
  const int g = blockIdx.x * 256 + threadIdx.x;  // 8192*32
  const int q = g >> 5, c = g & 31;
  if (c < NC) {
    float s = 0.f;
#pragma unroll
    for (int k = 0; k < NSLOT; ++k) s += ep[((size_t)k * NQ + q) * 32 + c];
    out[(size_t)q * NC + c] = s;
  } else if (c == NC) {  // ones-column == intensity
    float s = 0.f;
#pragma unroll
    for (int k = 0; k < NSLOT; ++k) s += ep[((size_t)k * NQ + q) * 32 + NC];
    out[(size_t)NQ * NC + q] = s;
  }
}

extern "C" void kernel_launch(void* const* d_in, const int* in_sizes, int n_in,
                              void* d_out, int out_size, void* d_ws, size_t ws_size,
                              hipStream_t stream) {
  const float* feat = (const float*)d_in[0];  // [8192][256]
  const float* exf  = (const float*)d_in[1];  // [16384][256]
  const float* exc  = (const float*)d_in[2];  // [16384][28]
  float* out = (float*)d_out;
  char* ws = (char*)d_ws;
  // ws layout: qn 4MB | kn 8MB | vt 1MB | ep 8MB  (~21MB)
  u16* qn = (u16*)ws;
  u16* kn = (u16*)(ws + 4194304);
  u16* vt = (u16*)(ws + 12582912);
  float* ep = (float*)(ws + 13631488);

  prep_kernel<<<dim3(6208), dim3(256), 0, stream>>>(feat, exf, exc, qn, kn, vt);
  fused_kernel<<<dim3(512), dim3(256), 0, stream>>>(qn, kn, vt, ep);
  reduce_kernel<<<dim3(NQ * 32 / 256), dim3(256), 0, stream>>>(ep, out);
}